// Round 5
// baseline (434.191 us; speedup 1.0000x reference)
//
#include <hip/hip_runtime.h>
#include <stdint.h>

#define N_ROWS 65536
#define NV 200
#define NH 128
#define NKD 32
#define NBKT 32768
#define ROWS_B 64
#define NBLK (N_ROWS/ROWS_B)   // 1024 blocks in k_main; 64 rows each

__device__ __forceinline__ uint32_t fkey(float x){
  uint32_t u = __float_as_uint(x);
  return (u & 0x80000000u) ? ~u : (u | 0x80000000u);
}

// ---------------- K0: extract tv/ti, tv histogram, tv partial stats ----------------
__global__ __launch_bounds__(256) void k_extract(
    const float* __restrict__ data, const int* __restrict__ tgt,
    float* __restrict__ tvArr, float* __restrict__ tiArr,
    unsigned int* __restrict__ histT, double* __restrict__ tvP){
  int i = blockIdx.x*256 + threadIdx.x;   // grid exactly N_ROWS threads
  int tg = *tgt;
  float v  = data[(size_t)i*600 + tg*3 + 0];
  float ti = data[(size_t)i*600 + tg*3 + 1];
  tvArr[i] = v; tiArr[i] = ti;
  atomicAdd(&histT[fkey(v)>>17], 1u);
  double s = (double)v, ss = (double)v*(double)v;
  float mn = v, mx = v;
  for (int off=32; off; off>>=1){
    s  += __shfl_down(s,  off);
    ss += __shfl_down(ss, off);
    mn = fminf(mn, __shfl_down(mn, off));
    mx = fmaxf(mx, __shfl_down(mx, off));
  }
  __shared__ double sd[4][4];
  int w = threadIdx.x >> 6;
  if ((threadIdx.x & 63) == 0){ sd[w][0]=s; sd[w][1]=ss; sd[w][2]=mn; sd[w][3]=mx; }
  __syncthreads();
  if (threadIdx.x == 0){
    double S=0, SS=0, MN=sd[0][2], MX=sd[0][3];
    for (int q=0;q<4;q++){ S+=sd[q][0]; SS+=sd[q][1]; MN=fmin(MN,sd[q][2]); MX=fmax(MX,sd[q][3]); }
    double* p = tvP + (size_t)blockIdx.x*4;
    p[0]=S; p[1]=SS; p[2]=MN; p[3]=MX;
  }
}

// ---------------- K1s: scan tv histogram -> midrank LUT (LDS, padded, conflict-free) ----------------
__global__ __launch_bounds__(256) void k_scan(unsigned int* __restrict__ histT){
  __shared__ unsigned int h[256*129];   // chunk c at h[c*129 .. +127]
  __shared__ unsigned int aux[256];
  int t = threadIdx.x;
  for (int idx=t; idx<NBKT; idx+=256) h[(idx>>7)*129 + (idx&127)] = histT[idx];
  __syncthreads();
  unsigned int s = 0;
  #pragma unroll 8
  for (int k=0;k<128;k++) s += h[t*129+k];      // bank = (t+k)%32 : conflict-free
  aux[t] = s; __syncthreads();
  for (int off=1; off<256; off<<=1){
    unsigned int v = (t>=off) ? aux[t-off] : 0u;
    __syncthreads();
    aux[t] += v;
    __syncthreads();
  }
  unsigned int run = aux[t] - s;       // exclusive prefix of chunk
  #pragma unroll 8
  for (int k=0;k<128;k++){
    unsigned int c = h[t*129+k];
    h[t*129+k] = __float_as_uint((float)run + 0.5f*((float)c - 1.f));
    run += c;
  }
  __syncthreads();
  for (int idx=t; idx<NBKT; idx+=256) histT[idx] = h[(idx>>7)*129 + (idx&127)];
}

// ---------------- K2a: main pass — direct per-thread-column streaming, no LDS ----------------
// thread t <-> column t; float2 strided loads (8B/lane, wave covers 768B contiguous);
// tv/ti are lane-invariant (broadcast loads); bktT written as per-thread contiguous u16 runs.
__global__ __launch_bounds__(256, 4) void k_main(
    const float* __restrict__ data, const float* __restrict__ tvArr,
    const float* __restrict__ tiArr, uint16_t* __restrict__ bktT,
    float* __restrict__ colP){
  int t = threadIdx.x, blk = blockIdx.x;
  int i0 = blk*ROWS_B;
  bool act = (t < NV);
  const float* base = data + (size_t)i0*600 + t*3;
  uint16_t* bout = bktT + (size_t)t*N_ROWS + i0;

  float facc[13];
  #pragma unroll
  for (int s=0;s<13;s++) facc[s]=0.f;
  float cmin = 3.4e38f, cmax = -3.4e38f;

  for (int c=0; c<4; ++c){
    int r0 = i0 + c*16;
    float2 v[16];
    if (act){
      #pragma unroll
      for (int r=0;r<16;r++)
        v[r] = *(const float2*)(base + (size_t)(c*16+r)*600);
    }
    // lane-invariant neighbor tv values and ti (broadcast loads)
    float tvv[18];
    #pragma unroll
    for (int k=0;k<18;k++){
      int i = r0 + k - 1;
      tvv[k] = (i>=0 && i<N_ROWS) ? tvArr[i] : 0.f;
    }
    float tii[16];
    #pragma unroll
    for (int k=0;k<16;k++) tii[k] = tiArr[r0+k];

    if (act){
      uint16_t bb[16];
      #pragma unroll
      for (int r=0;r<16;r++){
        float cv = v[r].x;
        float ci = v[r].y;                    // exactly 0.0 or 1.0
        float tv = tvv[r+1], tvm = tvv[r], tvp = tvv[r+2];
        float b  = (1.f-tii[r])*(1.f-ci);
        facc[0]+=cv;        facc[1]+=cv*cv;     facc[2]+=tv*cv;
        facc[3]+=ci;        facc[4]+=tv*ci;
        facc[5]+=b;         facc[6]+=tv*b;      facc[7]+=cv*b;
        facc[8]+=tv*cv*b;   facc[9]+=tv*tv*b;   facc[10]+=cv*cv*b;
        facc[11]+=tvp*cv;   facc[12]+=tvm*cv;
        cmin = fminf(cmin, cv); cmax = fmaxf(cmax, cv);
        bb[r] = (uint16_t)(fkey(cv)>>17);
      }
      *((uint4*)(bout + c*16))     = *((uint4*)(bb));
      *((uint4*)(bout + c*16 + 8)) = *((uint4*)(bb + 8));
    }
  }
  if (act){
    float* dst = colP + ((size_t)t*NBLK + blk)*16;
    #pragma unroll
    for (int s=0;s<13;s++) dst[s] = facc[s];
    dst[13]=cmin; dst[14]=cmax;
  }
}

// ---------------- K2c: combine per-column partials ----------------
__global__ __launch_bounds__(256) void k_comb_cols(const float* __restrict__ colP,
                                                   double* __restrict__ colStats){
  int j = blockIdx.x, t = threadIdx.x;
  double a[13];
  #pragma unroll
  for (int s=0;s<13;s++) a[s]=0.0;
  float mn = 3.4e38f, mx = -3.4e38f;
  for (int b=t; b<NBLK; b+=256){
    const float* p = colP + ((size_t)j*NBLK + b)*16;
    #pragma unroll
    for (int s=0;s<13;s++) a[s] += (double)p[s];
    mn = fminf(mn, p[13]); mx = fmaxf(mx, p[14]);
  }
  for (int off=32; off; off>>=1){
    #pragma unroll
    for (int s=0;s<13;s++) a[s] += __shfl_down(a[s], off);
    mn = fminf(mn, __shfl_down(mn, off));
    mx = fmaxf(mx, __shfl_down(mx, off));
  }
  __shared__ double sd[4][15];
  int w = t >> 6;
  if ((t & 63) == 0){
    #pragma unroll
    for (int s=0;s<13;s++) sd[w][s]=a[s];
    sd[w][13]=(double)mn; sd[w][14]=(double)mx;
  }
  __syncthreads();
  if (t == 0){
    double* d = colStats + (size_t)j*16;
    #pragma unroll
    for (int s=0;s<13;s++) d[s] = sd[0][s]+sd[1][s]+sd[2][s]+sd[3][s];
    double MN=sd[0][13], MX=sd[0][14];
    for (int q=1;q<4;q++){ MN=fmin(MN,sd[q][13]); MX=fmax(MX,sd[q][14]); }
    d[13]=MN; d[14]=MX;
  }
}

// ---------------- K2b: per-column Spearman numerator (1024 thr, padded LDS hist) ----------------
// target midranks computed on the fly from the histT LUT (k_trank fused away)
__global__ __launch_bounds__(1024, 1) void k_rank(const uint16_t* __restrict__ bktT,
                                                  const float* __restrict__ tvArr,
                                                  const unsigned int* __restrict__ histT,
                                                  double* __restrict__ colStats){
  __shared__ unsigned int h[1024*33];   // 135,168 B; bucket b at h[(b>>5)*33 + (b&31)]
  __shared__ unsigned int aux[1024];
  __shared__ double daux[16];
  int t = threadIdx.x, j = blockIdx.x;
  const uint16_t* col = bktT + (size_t)j*N_ROWS;
  for (int idx=t; idx<1024*33; idx+=1024) h[idx]=0u;
  __syncthreads();
  for (int k=0;k<N_ROWS/1024;k++){
    int b = (int)col[t + k*1024];
    atomicAdd(&h[(b>>5)*33 + (b&31)], 1u);
  }
  __syncthreads();
  unsigned int s = 0;
  #pragma unroll 8
  for (int k=0;k<32;k++) s += h[t*33+k];        // bank = (t+k)%32 : conflict-free
  aux[t]=s; __syncthreads();
  for (int off=1; off<1024; off<<=1){
    unsigned int v = (t>=off) ? aux[t-off] : 0u;
    __syncthreads();
    aux[t] += v;
    __syncthreads();
  }
  unsigned int run = aux[t] - s;
  #pragma unroll 8
  for (int k=0;k<32;k++){
    unsigned int c = h[t*33+k];
    h[t*33+k] = __float_as_uint((float)run + 0.5f*((float)c - 1.f));
    run += c;
  }
  __syncthreads();
  double srr = 0.0;
  for (int k=0;k<N_ROWS/1024;k++){
    int i = t + k*1024;
    int b = (int)col[i];
    float tr = __uint_as_float(histT[fkey(tvArr[i])>>17]);
    srr += (double)tr * (double)__uint_as_float(h[(b>>5)*33 + (b&31)]);
  }
  for (int off=32; off; off>>=1) srr += __shfl_down(srr, off);
  if ((t&63)==0) daux[t>>6] = srr;
  __syncthreads();
  if (t==0){
    double s16=0;
    for (int q=0;q<16;q++) s16 += daux[q];
    colStats[(size_t)j*16 + 15] = s16;
  }
}

// ---------------- K5: features + attention/MLP head (tv-stat combine fused in) ----------------
__device__ __forceinline__ float gelu_t(float x){
  float x3 = x*x*x;
  return 0.5f*x*(1.f + tanhf(0.7978845608f*(x + 0.044715f*x3)));
}

__global__ __launch_bounds__(128) void k_head(
    const float* __restrict__ te, const float* __restrict__ ne, const float* __restrict__ data,
    const float* __restrict__ Wpair, const float* __restrict__ bpair,
    const float* __restrict__ Wq, const float* __restrict__ bq,
    const float* __restrict__ Wk, const float* __restrict__ bk,
    const float* __restrict__ W1, const float* __restrict__ b1,
    const float* __restrict__ lns, const float* __restrict__ lno,
    const float* __restrict__ W2, const float* __restrict__ b2,
    const float* __restrict__ W3, const float* __restrict__ b3,
    const float* __restrict__ Wd, const int* __restrict__ tgt,
    const double* __restrict__ colStats, const double* __restrict__ tvP,
    const float* __restrict__ tvArr, float* __restrict__ out){
  int j = blockIdx.x, t = threadIdx.x;
  int tg = *tgt;

  // --- tv stats from 256 partials (redundant per block; ~1 us total, all L2-hot) ---
  __shared__ double tvsd[2][4];
  {
    double s  = tvP[t*4+0] + tvP[(t+128)*4+0];
    double ss = tvP[t*4+1] + tvP[(t+128)*4+1];
    double mn = fmin(tvP[t*4+2], tvP[(t+128)*4+2]);
    double mx = fmax(tvP[t*4+3], tvP[(t+128)*4+3]);
    for (int off=32; off; off>>=1){
      s  += __shfl_down(s,  off);
      ss += __shfl_down(ss, off);
      mn = fmin(mn, __shfl_down(mn, off));
      mx = fmax(mx, __shfl_down(mx, off));
    }
    int w = t>>6;
    if ((t&63)==0){ tvsd[w][0]=s; tvsd[w][1]=ss; tvsd[w][2]=mn; tvsd[w][3]=mx; }
    __syncthreads();
  }
  double S_t  = tvsd[0][0] + tvsd[1][0];
  double S_tt = tvsd[0][1] + tvsd[1][1];
  float tmin  = (float)fmin(tvsd[0][2], tvsd[1][2]);
  float tmax  = (float)fmax(tvsd[0][3], tvsd[1][3]);

  const double* cs = colStats + (size_t)j*16;
  double S_c=cs[0], S_cc=cs[1], S_tc=cs[2], S_ci=cs[3], S_ti=cs[4], S_b=cs[5],
         S_tb=cs[6], S_cb=cs[7], S_tcb=cs[8], S_ttb=cs[9], S_ccb=cs[10], L=cs[11], R=cs[12];
  float cmin=(float)cs[13], cmax=(float)cs[14];
  double S_rr=cs[15];
  float tv0=tvArr[0], tvN=tvArr[N_ROWS-1];
  float cv0=data[j*3], cvN=data[(size_t)(N_ROWS-1)*600 + j*3];
  const double Nd = (double)N_ROWS;
  double n = S_b + 1e-8;
  double tmean=S_tb/n, cmean=S_cb/n;
  double cov=(S_tcb - tmean*S_cb - cmean*S_tb + tmean*cmean*S_b)/n;
  double t2=S_ttb - 2.0*tmean*S_tb + tmean*tmean*S_b;
  double c2=S_ccb - 2.0*cmean*S_cb + cmean*cmean*S_b;
  double tstd=sqrt(t2/n + 1e-8), cstd=sqrt(c2/n + 1e-8);
  double corr = cov/(tstd*cstd + 1e-8);
  double mi = -0.5*log(1.0 - fmin(corr*corr, 0.99) + 1e-8);
  float ovn = fminf(tmax,cmax) - fmaxf(tmin,cmin);
  float ovd = fmaxf(tmax-tmin, cmax-cmin) + 1e-8f;
  float overlap = fmaxf(0.f, ovn/ovd);
  double M = Nd - 1.0;
  double Sa=S_t-(double)tv0, Saa=S_tt-(double)tv0*(double)tv0;
  double Sb2=S_c-(double)cvN, Sbb=S_cc-(double)cvN*(double)cvN;
  double lnum = L - Sa*Sb2/M;
  double lden2 = (Saa - Sa*Sa/M)*(Sbb - Sb2*Sb2/M);
  double lag = (lden2 > 0.0) ? lnum/sqrt(lden2) : 0.0;
  double Sa2=S_t-(double)tvN, Saa2=S_tt-(double)tvN*(double)tvN;
  double Sc2=S_c-(double)cv0, Scc2=S_cc-(double)cv0*(double)cv0;
  double rnum = R - Sa2*Sc2/M;
  double rden2 = (Saa2 - Sa2*Sa2/M)*(Scc2 - Sc2*Sc2/M);
  double rev = (rden2 > 0.0) ? rnum/sqrt(rden2) : 0.0;
  double var_t = S_tt/Nd - (S_t/Nd)*(S_t/Nd);
  double var_c = S_cc/Nd - (S_c/Nd)*(S_c/Nd);
  double coef = corr*sqrt(var_t)/(sqrt(var_c) + 1e-8);
  double covf = S_tc/Nd - (S_t/Nd)*(S_c/Nd);
  double var_res = var_t + coef*coef*var_c - 2.0*coef*covf;
  double var_ratio = var_res/(var_t + 1e-8);
  double t_int = S_ti/(S_ci + 1e-8);
  double t_no  = (S_t - S_ti)/((Nd - S_ci) + 1e-8);
  double effect = fabs(t_int - t_no);
  const double m_ = (Nd-1.0)*0.5;
  double rank_corr = (S_rr - Nd*m_*m_) / (Nd*(Nd*Nd-1.0)/12.0);
  float pf[11];
  pf[0]=(float)corr; pf[1]=(float)fabs(corr); pf[2]=(float)(corr*corr); pf[3]=(float)mi;
  pf[4]=overlap; pf[5]=(float)effect; pf[6]=(float)rank_corr;
  pf[7]=(float)((corr>0.0)-(corr<0.0)); pf[8]=(float)lag; pf[9]=(float)rev; pf[10]=(float)var_ratio;
  if (j == tg){
    #pragma unroll
    for (int q=0;q<11;q++) pf[q]=0.f;
  }
  // --- MLP head ---
  const float* nej = ne + (size_t)j*NH;
  float h = b1[t];
  for (int e=0;e<NH;e++) h += te[e]*W1[e*NH + t];
  for (int e=0;e<NH;e++) h += nej[e]*W1[(NH+e)*NH + t];
  #pragma unroll
  for (int f=0;f<11;f++) h += 10.f*pf[f]*W1[(2*NH+f)*NH + t];
  h = gelu_t(h);
  __shared__ float redW[2];
  __shared__ float hnS[NH];
  __shared__ float h2S[64];
  float v = h;
  for (int off=32; off; off>>=1) v += __shfl_down(v, off);
  if ((t&63)==0) redW[t>>6]=v;
  __syncthreads();
  float mu = (redW[0]+redW[1])*(1.f/128.f);
  __syncthreads();
  float d = h - mu;
  v = d*d;
  for (int off=32; off; off>>=1) v += __shfl_down(v, off);
  if ((t&63)==0) redW[t>>6]=v;
  __syncthreads();
  float var = (redW[0]+redW[1])*(1.f/128.f);
  float hn = d/sqrtf(var + 1e-5f)*lns[t] + lno[t];
  hnS[t] = hn;
  __syncthreads();
  if (t < 64){
    float h2 = b2[t];
    for (int o=0;o<NH;o++) h2 += hnS[o]*W2[o*64 + t];
    h2S[t] = gelu_t(h2);
  }
  __syncthreads();
  float netv = 0.f, scv = 0.f;
  if (t < 64){
    float v2 = h2S[t]*W3[t];
    for (int off=32; off; off>>=1) v2 += __shfl_down(v2, off);
    if (t==0) netv = v2 + b3[0];
  }
  if (t < 32){
    float q = bq[t], k = bk[t] + bpair[t];
    for (int e=0;e<NH;e++){ q += te[e]*Wq[e*NKD + t]; k += nej[e]*Wk[e*NKD + t]; }
    #pragma unroll
    for (int f=0;f<11;f++) k += pf[f]*Wpair[f*NKD + t];
    float sc = k*q;
    for (int off=16; off; off>>=1) sc += __shfl_down(sc, off, 32);
    if (t==0) scv = sc/sqrtf(32.f);
  }
  if (t == 0){
    float direct = pf[0]*Wd[0] + pf[8]*Wd[1] + pf[10]*Wd[2];
    out[j] = scv + netv + 0.5f*direct;
  }
}

// ---------------- launcher ----------------
extern "C" void kernel_launch(void* const* d_in, const int* in_sizes, int n_in,
                              void* d_out, int out_size, void* d_ws, size_t ws_size,
                              hipStream_t stream) {
  const float* te    = (const float*)d_in[0];
  const float* ne    = (const float*)d_in[1];
  const float* data  = (const float*)d_in[2];
  const float* Wpair = (const float*)d_in[3];
  const float* bpair = (const float*)d_in[4];
  const float* Wq    = (const float*)d_in[5];
  const float* bq    = (const float*)d_in[6];
  const float* Wk    = (const float*)d_in[7];
  const float* bk    = (const float*)d_in[8];
  const float* W1    = (const float*)d_in[9];
  const float* b1    = (const float*)d_in[10];
  const float* lns   = (const float*)d_in[11];
  const float* lno   = (const float*)d_in[12];
  const float* W2    = (const float*)d_in[13];
  const float* b2    = (const float*)d_in[14];
  const float* W3    = (const float*)d_in[15];
  const float* b3    = (const float*)d_in[16];
  const float* Wd    = (const float*)d_in[17];
  const int*   tgt   = (const int*)d_in[18];
  float* out = (float*)d_out;

  char* ws = (char*)d_ws;
  size_t off = 0;
  auto alloc = [&](size_t bytes)->char*{
    char* p = ws + off;
    off = (off + bytes + 255) & ~(size_t)255;
    return p;
  };
  uint16_t*     bktT     = (uint16_t*)    alloc((size_t)NV*N_ROWS*2);
  float*        tvArr    = (float*)       alloc(N_ROWS*4);
  float*        tiArr    = (float*)       alloc(N_ROWS*4);
  unsigned int* histT    = (unsigned int*)alloc(NBKT*4);
  double*       tvP      = (double*)      alloc(256*4*8);
  float*        colP     = (float*)       alloc((size_t)NV*NBLK*16*4);
  double*       colStats = (double*)      alloc((size_t)NV*16*8);
  if (off > ws_size) return;  // insufficient workspace -> fail visibly

  hipMemsetAsync(histT, 0, NBKT*4, stream);
  k_extract<<<dim3(N_ROWS/256), dim3(256), 0, stream>>>(data, tgt, tvArr, tiArr, histT, tvP);
  k_scan<<<dim3(1), dim3(256), 0, stream>>>(histT);
  k_main<<<dim3(NBLK), dim3(256), 0, stream>>>(data, tvArr, tiArr, bktT, colP);
  k_comb_cols<<<dim3(NV), dim3(256), 0, stream>>>(colP, colStats);
  k_rank<<<dim3(NV), dim3(1024), 0, stream>>>(bktT, tvArr, histT, colStats);
  k_head<<<dim3(NV), dim3(128), 0, stream>>>(te, ne, data, Wpair, bpair, Wq, bq, Wk, bk,
                                             W1, b1, lns, lno, W2, b2, W3, b3, Wd, tgt,
                                             colStats, tvP, tvArr, out);
}

// Round 6
// 393.241 us; speedup vs baseline: 1.1041x; 1.1041x over previous
//
#include <hip/hip_runtime.h>
#include <stdint.h>

#define N_ROWS 65536
#define NV 200
#define NH 128
#define NKD 32
#define NBKT 32768
#define ROWS_B 64
#define NBLK (N_ROWS/ROWS_B)   // 1024 blocks in k_main; 64 rows each

__device__ __forceinline__ uint32_t fkey(float x){
  uint32_t u = __float_as_uint(x);
  return (u & 0x80000000u) ? ~u : (u | 0x80000000u);
}

// ---------------- K0: extract tv/ti, tv histogram, tv partial stats ----------------
__global__ __launch_bounds__(256) void k_extract(
    const float* __restrict__ data, const int* __restrict__ tgt,
    float* __restrict__ tvArr, float* __restrict__ tiArr,
    unsigned int* __restrict__ histT, double* __restrict__ tvP){
  int i = blockIdx.x*256 + threadIdx.x;   // grid exactly N_ROWS threads
  int tg = *tgt;
  float v  = data[(size_t)i*600 + tg*3 + 0];
  float ti = data[(size_t)i*600 + tg*3 + 1];
  tvArr[i] = v; tiArr[i] = ti;
  atomicAdd(&histT[fkey(v)>>17], 1u);
  double s = (double)v, ss = (double)v*(double)v;
  float mn = v, mx = v;
  for (int off=32; off; off>>=1){
    s  += __shfl_down(s,  off);
    ss += __shfl_down(ss, off);
    mn = fminf(mn, __shfl_down(mn, off));
    mx = fmaxf(mx, __shfl_down(mx, off));
  }
  __shared__ double sd[4][4];
  int w = threadIdx.x >> 6;
  if ((threadIdx.x & 63) == 0){ sd[w][0]=s; sd[w][1]=ss; sd[w][2]=mn; sd[w][3]=mx; }
  __syncthreads();
  if (threadIdx.x == 0){
    double S=0, SS=0, MN=sd[0][2], MX=sd[0][3];
    for (int q=0;q<4;q++){ S+=sd[q][0]; SS+=sd[q][1]; MN=fmin(MN,sd[q][2]); MX=fmax(MX,sd[q][3]); }
    double* p = tvP + (size_t)blockIdx.x*4;
    p[0]=S; p[1]=SS; p[2]=MN; p[3]=MX;
  }
}

// ---------------- K1s: scan tv histogram -> midrank LUT (LDS, padded, conflict-free) ----------------
__global__ __launch_bounds__(256) void k_scan(unsigned int* __restrict__ histT){
  __shared__ unsigned int h[256*129];   // chunk c at h[c*129 .. +127]
  __shared__ unsigned int aux[256];
  int t = threadIdx.x;
  for (int idx=t; idx<NBKT; idx+=256) h[(idx>>7)*129 + (idx&127)] = histT[idx];
  __syncthreads();
  unsigned int s = 0;
  #pragma unroll 8
  for (int k=0;k<128;k++) s += h[t*129+k];      // bank = (t+k)%32 : conflict-free
  aux[t] = s; __syncthreads();
  for (int off=1; off<256; off<<=1){
    unsigned int v = (t>=off) ? aux[t-off] : 0u;
    __syncthreads();
    aux[t] += v;
    __syncthreads();
  }
  unsigned int run = aux[t] - s;       // exclusive prefix of chunk
  #pragma unroll 8
  for (int k=0;k<128;k++){
    unsigned int c = h[t*129+k];
    h[t*129+k] = __float_as_uint((float)run + 0.5f*((float)c - 1.f));
    run += c;
  }
  __syncthreads();
  for (int idx=t; idx<NBKT; idx+=256) histT[idx] = h[(idx>>7)*129 + (idx&127)];
}

// ---------------- K1b: materialize tv midranks (one gather per row) ----------------
__global__ __launch_bounds__(256) void k_trank(const float* __restrict__ tvArr,
                                               const unsigned int* __restrict__ histT,
                                               float* __restrict__ trArr){
  int i = blockIdx.x*256 + threadIdx.x;
  trArr[i] = __uint_as_float(histT[fkey(tvArr[i])>>17]);
}

// ---------------- K2a: main pass — direct per-thread-column streaming, no LDS ----------------
// thread t <-> column t; float2 strided loads (8B/lane, wave covers 768B contiguous);
// bucket codes buffered in regs, written as ONE 128-B contiguous burst at the end
// (full-line writes -> no L2 partial-line eviction / RMW amplification).
__global__ __launch_bounds__(256, 4) void k_main(
    const float* __restrict__ data, const float* __restrict__ tvArr,
    const float* __restrict__ tiArr, uint16_t* __restrict__ bktT,
    float* __restrict__ colP){
  int t = threadIdx.x, blk = blockIdx.x;
  int i0 = blk*ROWS_B;
  bool act = (t < NV);
  const float* base = data + (size_t)i0*600 + t*3;

  float facc[13];
  #pragma unroll
  for (int s=0;s<13;s++) facc[s]=0.f;
  float cmin = 3.4e38f, cmax = -3.4e38f;
  uint16_t bb[ROWS_B];

  #pragma unroll
  for (int c=0; c<4; ++c){
    int r0 = i0 + c*16;
    float2 v[16];
    if (act){
      #pragma unroll
      for (int r=0;r<16;r++)
        v[r] = *(const float2*)(base + (size_t)(c*16+r)*600);
    }
    // lane-invariant neighbor tv values and ti (broadcast loads)
    float tvv[18];
    #pragma unroll
    for (int k=0;k<18;k++){
      int i = r0 + k - 1;
      tvv[k] = (i>=0 && i<N_ROWS) ? tvArr[i] : 0.f;
    }
    float tii[16];
    #pragma unroll
    for (int k=0;k<16;k++) tii[k] = tiArr[r0+k];

    if (act){
      #pragma unroll
      for (int r=0;r<16;r++){
        float cv = v[r].x;
        float ci = v[r].y;                    // exactly 0.0 or 1.0
        float tv = tvv[r+1], tvm = tvv[r], tvp = tvv[r+2];
        float b  = (1.f-tii[r])*(1.f-ci);
        facc[0]+=cv;        facc[1]+=cv*cv;     facc[2]+=tv*cv;
        facc[3]+=ci;        facc[4]+=tv*ci;
        facc[5]+=b;         facc[6]+=tv*b;      facc[7]+=cv*b;
        facc[8]+=tv*cv*b;   facc[9]+=tv*tv*b;   facc[10]+=cv*cv*b;
        facc[11]+=tvp*cv;   facc[12]+=tvm*cv;
        cmin = fminf(cmin, cv); cmax = fmaxf(cmax, cv);
        bb[c*16+r] = (uint16_t)(fkey(cv)>>17);
      }
    }
  }
  if (act){
    // single contiguous 128-B burst: two full 64-B lines per thread
    uint4* bo = (uint4*)(bktT + (size_t)t*N_ROWS + i0);
    #pragma unroll
    for (int q=0;q<8;q++) bo[q] = ((const uint4*)bb)[q];
    float* dst = colP + ((size_t)t*NBLK + blk)*16;
    #pragma unroll
    for (int s=0;s<13;s++) dst[s] = facc[s];
    dst[13]=cmin; dst[14]=cmax;
  }
}

// ---------------- K2b: per-column partial-combine + Spearman numerator ----------------
// block j: (a) combine colP partials for column j -> colStats[j][0..14]
//          (b) histogram midranks over bktT column j -> colStats[j][15]
__global__ __launch_bounds__(1024, 1) void k_rank(const uint16_t* __restrict__ bktT,
                                                  const float* __restrict__ trArr,
                                                  const float* __restrict__ colP,
                                                  double* __restrict__ colStats){
  __shared__ unsigned int h[1024*33];   // 135,168 B; bucket b at h[(b>>5)*33 + (b&31)]
  __shared__ unsigned int aux[1024];
  __shared__ double daux[16];
  __shared__ double sdc[16][15];
  int t = threadIdx.x, j = blockIdx.x;
  const uint16_t* col = bktT + (size_t)j*N_ROWS;
  for (int idx=t; idx<1024*33; idx+=1024) h[idx]=0u;

  // ---- (a) combine partials: thread t owns partial t (NBLK==1024) ----
  {
    const float* p = colP + ((size_t)j*NBLK + t)*16;
    double a[13];
    #pragma unroll
    for (int s=0;s<13;s++) a[s] = (double)p[s];
    float mn = p[13], mx = p[14];
    for (int off=32; off; off>>=1){
      #pragma unroll
      for (int s=0;s<13;s++) a[s] += __shfl_down(a[s], off);
      mn = fminf(mn, __shfl_down(mn, off));
      mx = fmaxf(mx, __shfl_down(mx, off));
    }
    int w = t >> 6;
    if ((t & 63) == 0){
      #pragma unroll
      for (int s=0;s<13;s++) sdc[w][s]=a[s];
      sdc[w][13]=(double)mn; sdc[w][14]=(double)mx;
    }
    __syncthreads();
    if (t == 0){
      double* d = colStats + (size_t)j*16;
      #pragma unroll
      for (int s=0;s<13;s++){
        double acc=0;
        for (int q=0;q<16;q++) acc += sdc[q][s];
        d[s]=acc;
      }
      double MN=sdc[0][13], MX=sdc[0][14];
      for (int q=1;q<16;q++){ MN=fmin(MN,sdc[q][13]); MX=fmax(MX,sdc[q][14]); }
      d[13]=MN; d[14]=MX;
    }
  }

  // ---- (b) histogram ----
  for (int k=0;k<N_ROWS/1024;k++){
    int b = (int)col[t + k*1024];
    atomicAdd(&h[(b>>5)*33 + (b&31)], 1u);
  }
  __syncthreads();
  unsigned int s = 0;
  #pragma unroll 8
  for (int k=0;k<32;k++) s += h[t*33+k];        // bank = (t+k)%32 : conflict-free
  aux[t]=s; __syncthreads();
  for (int off=1; off<1024; off<<=1){
    unsigned int v = (t>=off) ? aux[t-off] : 0u;
    __syncthreads();
    aux[t] += v;
    __syncthreads();
  }
  unsigned int run = aux[t] - s;
  #pragma unroll 8
  for (int k=0;k<32;k++){
    unsigned int c = h[t*33+k];
    h[t*33+k] = __float_as_uint((float)run + 0.5f*((float)c - 1.f));
    run += c;
  }
  __syncthreads();
  double srr = 0.0;
  for (int k=0;k<N_ROWS/1024;k++){
    int i = t + k*1024;
    int b = (int)col[i];
    srr += (double)trArr[i] * (double)__uint_as_float(h[(b>>5)*33 + (b&31)]);
  }
  for (int off=32; off; off>>=1) srr += __shfl_down(srr, off);
  if ((t&63)==0) daux[t>>6] = srr;
  __syncthreads();
  if (t==0){
    double s16=0;
    for (int q=0;q<16;q++) s16 += daux[q];
    colStats[(size_t)j*16 + 15] = s16;
  }
}

// ---------------- K5: features + attention/MLP head (tv-stat combine fused in) ----------------
__device__ __forceinline__ float gelu_t(float x){
  float x3 = x*x*x;
  return 0.5f*x*(1.f + tanhf(0.7978845608f*(x + 0.044715f*x3)));
}

__global__ __launch_bounds__(128) void k_head(
    const float* __restrict__ te, const float* __restrict__ ne, const float* __restrict__ data,
    const float* __restrict__ Wpair, const float* __restrict__ bpair,
    const float* __restrict__ Wq, const float* __restrict__ bq,
    const float* __restrict__ Wk, const float* __restrict__ bk,
    const float* __restrict__ W1, const float* __restrict__ b1,
    const float* __restrict__ lns, const float* __restrict__ lno,
    const float* __restrict__ W2, const float* __restrict__ b2,
    const float* __restrict__ W3, const float* __restrict__ b3,
    const float* __restrict__ Wd, const int* __restrict__ tgt,
    const double* __restrict__ colStats, const double* __restrict__ tvP,
    const float* __restrict__ tvArr, float* __restrict__ out){
  int j = blockIdx.x, t = threadIdx.x;
  int tg = *tgt;

  // --- tv stats from 256 partials (redundant per block; L2-hot) ---
  __shared__ double tvsd[2][4];
  {
    double s  = tvP[t*4+0] + tvP[(t+128)*4+0];
    double ss = tvP[t*4+1] + tvP[(t+128)*4+1];
    double mn = fmin(tvP[t*4+2], tvP[(t+128)*4+2]);
    double mx = fmax(tvP[t*4+3], tvP[(t+128)*4+3]);
    for (int off=32; off; off>>=1){
      s  += __shfl_down(s,  off);
      ss += __shfl_down(ss, off);
      mn = fmin(mn, __shfl_down(mn, off));
      mx = fmax(mx, __shfl_down(mx, off));
    }
    int w = t>>6;
    if ((t&63)==0){ tvsd[w][0]=s; tvsd[w][1]=ss; tvsd[w][2]=mn; tvsd[w][3]=mx; }
    __syncthreads();
  }
  double S_t  = tvsd[0][0] + tvsd[1][0];
  double S_tt = tvsd[0][1] + tvsd[1][1];
  float tmin  = (float)fmin(tvsd[0][2], tvsd[1][2]);
  float tmax  = (float)fmax(tvsd[0][3], tvsd[1][3]);

  const double* cs = colStats + (size_t)j*16;
  double S_c=cs[0], S_cc=cs[1], S_tc=cs[2], S_ci=cs[3], S_ti=cs[4], S_b=cs[5],
         S_tb=cs[6], S_cb=cs[7], S_tcb=cs[8], S_ttb=cs[9], S_ccb=cs[10], L=cs[11], R=cs[12];
  float cmin=(float)cs[13], cmax=(float)cs[14];
  double S_rr=cs[15];
  float tv0=tvArr[0], tvN=tvArr[N_ROWS-1];
  float cv0=data[j*3], cvN=data[(size_t)(N_ROWS-1)*600 + j*3];
  const double Nd = (double)N_ROWS;
  double n = S_b + 1e-8;
  double tmean=S_tb/n, cmean=S_cb/n;
  double cov=(S_tcb - tmean*S_cb - cmean*S_tb + tmean*cmean*S_b)/n;
  double t2=S_ttb - 2.0*tmean*S_tb + tmean*tmean*S_b;
  double c2=S_ccb - 2.0*cmean*S_cb + cmean*cmean*S_b;
  double tstd=sqrt(t2/n + 1e-8), cstd=sqrt(c2/n + 1e-8);
  double corr = cov/(tstd*cstd + 1e-8);
  double mi = -0.5*log(1.0 - fmin(corr*corr, 0.99) + 1e-8);
  float ovn = fminf(tmax,cmax) - fmaxf(tmin,cmin);
  float ovd = fmaxf(tmax-tmin, cmax-cmin) + 1e-8f;
  float overlap = fmaxf(0.f, ovn/ovd);
  double M = Nd - 1.0;
  double Sa=S_t-(double)tv0, Saa=S_tt-(double)tv0*(double)tv0;
  double Sb2=S_c-(double)cvN, Sbb=S_cc-(double)cvN*(double)cvN;
  double lnum = L - Sa*Sb2/M;
  double lden2 = (Saa - Sa*Sa/M)*(Sbb - Sb2*Sb2/M);
  double lag = (lden2 > 0.0) ? lnum/sqrt(lden2) : 0.0;
  double Sa2=S_t-(double)tvN, Saa2=S_tt-(double)tvN*(double)tvN;
  double Sc2=S_c-(double)cv0, Scc2=S_cc-(double)cv0*(double)cv0;
  double rnum = R - Sa2*Sc2/M;
  double rden2 = (Saa2 - Sa2*Sa2/M)*(Scc2 - Sc2*Sc2/M);
  double rev = (rden2 > 0.0) ? rnum/sqrt(rden2) : 0.0;
  double var_t = S_tt/Nd - (S_t/Nd)*(S_t/Nd);
  double var_c = S_cc/Nd - (S_c/Nd)*(S_c/Nd);
  double coef = corr*sqrt(var_t)/(sqrt(var_c) + 1e-8);
  double covf = S_tc/Nd - (S_t/Nd)*(S_c/Nd);
  double var_res = var_t + coef*coef*var_c - 2.0*coef*covf;
  double var_ratio = var_res/(var_t + 1e-8);
  double t_int = S_ti/(S_ci + 1e-8);
  double t_no  = (S_t - S_ti)/((Nd - S_ci) + 1e-8);
  double effect = fabs(t_int - t_no);
  const double m_ = (Nd-1.0)*0.5;
  double rank_corr = (S_rr - Nd*m_*m_) / (Nd*(Nd*Nd-1.0)/12.0);
  float pf[11];
  pf[0]=(float)corr; pf[1]=(float)fabs(corr); pf[2]=(float)(corr*corr); pf[3]=(float)mi;
  pf[4]=overlap; pf[5]=(float)effect; pf[6]=(float)rank_corr;
  pf[7]=(float)((corr>0.0)-(corr<0.0)); pf[8]=(float)lag; pf[9]=(float)rev; pf[10]=(float)var_ratio;
  if (j == tg){
    #pragma unroll
    for (int q=0;q<11;q++) pf[q]=0.f;
  }
  // --- MLP head ---
  const float* nej = ne + (size_t)j*NH;
  float h = b1[t];
  for (int e=0;e<NH;e++) h += te[e]*W1[e*NH + t];
  for (int e=0;e<NH;e++) h += nej[e]*W1[(NH+e)*NH + t];
  #pragma unroll
  for (int f=0;f<11;f++) h += 10.f*pf[f]*W1[(2*NH+f)*NH + t];
  h = gelu_t(h);
  __shared__ float redW[2];
  __shared__ float hnS[NH];
  __shared__ float h2S[64];
  float v = h;
  for (int off=32; off; off>>=1) v += __shfl_down(v, off);
  if ((t&63)==0) redW[t>>6]=v;
  __syncthreads();
  float mu = (redW[0]+redW[1])*(1.f/128.f);
  __syncthreads();
  float d = h - mu;
  v = d*d;
  for (int off=32; off; off>>=1) v += __shfl_down(v, off);
  if ((t&63)==0) redW[t>>6]=v;
  __syncthreads();
  float var = (redW[0]+redW[1])*(1.f/128.f);
  float hn = d/sqrtf(var + 1e-5f)*lns[t] + lno[t];
  hnS[t] = hn;
  __syncthreads();
  if (t < 64){
    float h2 = b2[t];
    for (int o=0;o<NH;o++) h2 += hnS[o]*W2[o*64 + t];
    h2S[t] = gelu_t(h2);
  }
  __syncthreads();
  float netv = 0.f, scv = 0.f;
  if (t < 64){
    float v2 = h2S[t]*W3[t];
    for (int off=32; off; off>>=1) v2 += __shfl_down(v2, off);
    if (t==0) netv = v2 + b3[0];
  }
  if (t < 32){
    float q = bq[t], k = bk[t] + bpair[t];
    for (int e=0;e<NH;e++){ q += te[e]*Wq[e*NKD + t]; k += nej[e]*Wk[e*NKD + t]; }
    #pragma unroll
    for (int f=0;f<11;f++) k += pf[f]*Wpair[f*NKD + t];
    float sc = k*q;
    for (int off=16; off; off>>=1) sc += __shfl_down(sc, off, 32);
    if (t==0) scv = sc/sqrtf(32.f);
  }
  if (t == 0){
    float direct = pf[0]*Wd[0] + pf[8]*Wd[1] + pf[10]*Wd[2];
    out[j] = scv + netv + 0.5f*direct;
  }
}

// ---------------- launcher ----------------
extern "C" void kernel_launch(void* const* d_in, const int* in_sizes, int n_in,
                              void* d_out, int out_size, void* d_ws, size_t ws_size,
                              hipStream_t stream) {
  const float* te    = (const float*)d_in[0];
  const float* ne    = (const float*)d_in[1];
  const float* data  = (const float*)d_in[2];
  const float* Wpair = (const float*)d_in[3];
  const float* bpair = (const float*)d_in[4];
  const float* Wq    = (const float*)d_in[5];
  const float* bq    = (const float*)d_in[6];
  const float* Wk    = (const float*)d_in[7];
  const float* bk    = (const float*)d_in[8];
  const float* W1    = (const float*)d_in[9];
  const float* b1    = (const float*)d_in[10];
  const float* lns   = (const float*)d_in[11];
  const float* lno   = (const float*)d_in[12];
  const float* W2    = (const float*)d_in[13];
  const float* b2    = (const float*)d_in[14];
  const float* W3    = (const float*)d_in[15];
  const float* b3    = (const float*)d_in[16];
  const float* Wd    = (const float*)d_in[17];
  const int*   tgt   = (const int*)d_in[18];
  float* out = (float*)d_out;

  char* ws = (char*)d_ws;
  size_t off = 0;
  auto alloc = [&](size_t bytes)->char*{
    char* p = ws + off;
    off = (off + bytes + 255) & ~(size_t)255;
    return p;
  };
  uint16_t*     bktT     = (uint16_t*)    alloc((size_t)NV*N_ROWS*2);
  float*        tvArr    = (float*)       alloc(N_ROWS*4);
  float*        tiArr    = (float*)       alloc(N_ROWS*4);
  float*        trArr    = (float*)       alloc(N_ROWS*4);
  unsigned int* histT    = (unsigned int*)alloc(NBKT*4);
  double*       tvP      = (double*)      alloc(256*4*8);
  float*        colP     = (float*)       alloc((size_t)NV*NBLK*16*4);
  double*       colStats = (double*)      alloc((size_t)NV*16*8);
  if (off > ws_size) return;  // insufficient workspace -> fail visibly

  hipMemsetAsync(histT, 0, NBKT*4, stream);
  k_extract<<<dim3(N_ROWS/256), dim3(256), 0, stream>>>(data, tgt, tvArr, tiArr, histT, tvP);
  k_scan<<<dim3(1), dim3(256), 0, stream>>>(histT);
  k_trank<<<dim3(N_ROWS/256), dim3(256), 0, stream>>>(tvArr, histT, trArr);
  k_main<<<dim3(NBLK), dim3(256), 0, stream>>>(data, tvArr, tiArr, bktT, colP);
  k_rank<<<dim3(NV), dim3(1024), 0, stream>>>(bktT, trArr, colP, colStats);
  k_head<<<dim3(NV), dim3(128), 0, stream>>>(te, ne, data, Wpair, bpair, Wq, bq, Wk, bk,
                                             W1, b1, lns, lno, W2, b2, W3, b3, Wd, tgt,
                                             colStats, tvP, tvArr, out);
}